// Round 1
// baseline (2516.166 us; speedup 1.0000x reference)
//
#include <hip/hip_runtime.h>
#include <hip/hip_bf16.h>

// Sizes (fixed by the reference, but derived from in_sizes at launch):
// V=50000, E=1600000, D=64, EF=16, node_in=74, NV=64.

__device__ __forceinline__ void lgkm_wait() {
  asm volatile("s_waitcnt lgkmcnt(0)" ::: "memory");
}

// ---------------------------------------------------------------- cnt kernel
__global__ void cnt_kernel(const int* __restrict__ ei, float* __restrict__ cnt, int E_) {
  int i = blockIdx.x * blockDim.x + threadIdx.x;
  if (i < E_) atomicAdd(&cnt[ei[E_ + i]], 1.0f);
}

// ------------------------------------------------------------- embed kernel
// h[r,c] = sum_k concat(Z[r,:],vm[r,:])[k] * nW[k,c] + nb[c]
__global__ __launch_bounds__(256, 2) void embed_kernel(
    const float* __restrict__ Z, const float* __restrict__ vm,
    const float* __restrict__ nW, const float* __restrict__ nb,
    float* __restrict__ h, int V_) {
  __shared__ alignas(16) float zbuf[4][80];
  const int lane = threadIdx.x & 63;
  const int wid  = threadIdx.x >> 6;
  float wc[74];
#pragma unroll
  for (int k = 0; k < 74; ++k) wc[k] = nW[k * 64 + lane];
  const float bc = nb[lane];
  const int nw = (gridDim.x * blockDim.x) >> 6;
  const int w0 = (blockIdx.x * blockDim.x + threadIdx.x) >> 6;
  float* zrow = zbuf[wid];
  for (int r = w0; r < V_; r += nw) {
    lgkm_wait();  // prior-iteration reads done before overwrite
    zrow[lane] = Z[(size_t)r * 64 + lane];
    if (lane < 10) zrow[64 + lane] = vm[(size_t)r * 10 + lane];
    lgkm_wait();
    float acc0 = bc, acc1 = 0.0f;
    const float4* z4 = reinterpret_cast<const float4*>(zrow);
#pragma unroll
    for (int k4 = 0; k4 < 16; ++k4) {
      float4 z = z4[k4];
      acc0 = fmaf(z.x, wc[4 * k4 + 0], acc0);
      acc1 = fmaf(z.y, wc[4 * k4 + 1], acc1);
      acc0 = fmaf(z.z, wc[4 * k4 + 2], acc0);
      acc1 = fmaf(z.w, wc[4 * k4 + 3], acc1);
    }
#pragma unroll
    for (int k = 64; k < 74; ++k) acc0 = fmaf(zrow[k], wc[k], acc0);
    h[(size_t)r * 64 + lane] = acc0 + acc1;
  }
}

// -------------------------------------------------------------- edge kernel
// One wave per edge. lane = output column.
// msg = relu([h[src],ea[e]] @ W1 + b1) @ W2 + b2 ; atomicAdd into agg[dst].
__global__ __launch_bounds__(256, 2) void edge_kernel(
    const float* __restrict__ h, const float* __restrict__ ea,
    const int* __restrict__ ei,
    const float* __restrict__ W1, const float* __restrict__ b1,
    const float* __restrict__ W2, const float* __restrict__ b2,
    float* __restrict__ agg, int E_) {
  __shared__ alignas(16) float zbuf[4][96];
  __shared__ alignas(16) float tbuf[4][64];
  const int lane = threadIdx.x & 63;
  const int wid  = threadIdx.x >> 6;
  float w1c[80], w2c[64];
#pragma unroll
  for (int k = 0; k < 80; ++k) w1c[k] = W1[k * 64 + lane];
#pragma unroll
  for (int k = 0; k < 64; ++k) w2c[k] = W2[k * 64 + lane];
  const float b1c = b1[lane];
  const float b2c = b2[lane];
  const int nw = (gridDim.x * blockDim.x) >> 6;
  const int w0 = (blockIdx.x * blockDim.x + threadIdx.x) >> 6;
  float* zrow = zbuf[wid];
  float* trow = tbuf[wid];
  for (int e = w0; e < E_; e += nw) {
    const int src = ei[e];
    const int dst = ei[E_ + e];
    const float zv = h[(size_t)src * 64 + lane];
    lgkm_wait();  // prior-iteration LDS reads complete before overwrite
    zrow[lane] = zv;
    if (lane < 16) zrow[64 + lane] = ea[(size_t)e * 16 + lane];
    lgkm_wait();  // writes visible to whole wave
    float acc0 = b1c, acc1 = 0.0f;
    const float4* z4 = reinterpret_cast<const float4*>(zrow);
#pragma unroll
    for (int k4 = 0; k4 < 20; ++k4) {
      float4 z = z4[k4];
      acc0 = fmaf(z.x, w1c[4 * k4 + 0], acc0);
      acc1 = fmaf(z.y, w1c[4 * k4 + 1], acc1);
      acc0 = fmaf(z.z, w1c[4 * k4 + 2], acc0);
      acc1 = fmaf(z.w, w1c[4 * k4 + 3], acc1);
    }
    trow[lane] = fmaxf(acc0 + acc1, 0.0f);
    lgkm_wait();
    float s0 = b2c, s1 = 0.0f;
    const float4* t4 = reinterpret_cast<const float4*>(trow);
#pragma unroll
    for (int k4 = 0; k4 < 16; ++k4) {
      float4 t = t4[k4];
      s0 = fmaf(t.x, w2c[4 * k4 + 0], s0);
      s1 = fmaf(t.y, w2c[4 * k4 + 1], s1);
      s0 = fmaf(t.z, w2c[4 * k4 + 2], s0);
      s1 = fmaf(t.w, w2c[4 * k4 + 3], s1);
    }
    atomicAdd(&agg[(size_t)dst * 64 + lane], s0 + s1);
  }
}

// ---------------------------------------------------------- finalize kernel
// agg[r,:] = LN(h[r,:] + agg[r,:]/max(cnt[r],1)) * g + be   (in-place in agg)
__global__ __launch_bounds__(256) void finalize_kernel(
    const float* __restrict__ h, float* __restrict__ agg,
    const float* __restrict__ cnt, const float* __restrict__ g,
    const float* __restrict__ be, int V_) {
  const int lane = threadIdx.x & 63;
  const int nw = (gridDim.x * blockDim.x) >> 6;
  const int w0 = (blockIdx.x * blockDim.x + threadIdx.x) >> 6;
  const float gc = g[lane], bc = be[lane];
  for (int r = w0; r < V_; r += nw) {
    float x = h[(size_t)r * 64 + lane] +
              agg[(size_t)r * 64 + lane] / fmaxf(cnt[r], 1.0f);
    float m = x;
#pragma unroll
    for (int off = 32; off; off >>= 1) m += __shfl_xor(m, off);
    m *= (1.0f / 64.0f);
    float d = x - m;
    float v = d * d;
#pragma unroll
    for (int off = 32; off; off >>= 1) v += __shfl_xor(v, off);
    v *= (1.0f / 64.0f);
    agg[(size_t)r * 64 + lane] = d * rsqrtf(v + 1e-5f) * gc + bc;
  }
}

// ------------------------------------------------------------- props kernel
// props = relu(vf @ pW1 + pb1) @ pW2 + pb2   [64,64], single wave-ish block
__global__ void props_kernel(const float* __restrict__ vf,
                             const float* __restrict__ pW1, const float* __restrict__ pb1,
                             const float* __restrict__ pW2, const float* __restrict__ pb2,
                             float* __restrict__ props) {
  __shared__ float tbuf[64];
  const int c = threadIdx.x;  // 0..63
  float w1c[8], w2c[64];
#pragma unroll
  for (int i = 0; i < 8; ++i) w1c[i] = pW1[i * 64 + c];
#pragma unroll
  for (int k = 0; k < 64; ++k) w2c[k] = pW2[k * 64 + c];
  const float b1c = pb1[c], b2c = pb2[c];
  for (int v = 0; v < 64; ++v) {
    float acc = b1c;
#pragma unroll
    for (int i = 0; i < 8; ++i) acc = fmaf(vf[v * 8 + i], w1c[i], acc);
    tbuf[c] = fmaxf(acc, 0.0f);
    __syncthreads();
    float s = b2c;
#pragma unroll
    for (int k = 0; k < 64; ++k) s = fmaf(tbuf[k], w2c[k], s);
    props[v * 64 + c] = s;
    __syncthreads();
  }
}

// -------------------------------------------------------------- final kernel
// out[v,:] = LN(h[cur[v],:] + props[v,:]) * rg + rb
__global__ void final_kernel(const float* __restrict__ h, const int* __restrict__ cur,
                             const float* __restrict__ props,
                             const float* __restrict__ rg, const float* __restrict__ rb,
                             float* __restrict__ out) {
  const int v = blockIdx.x;
  const int c = threadIdx.x;  // 64 threads
  const int node = cur[v];
  float x = h[(size_t)node * 64 + c] + props[v * 64 + c];
  float m = x;
#pragma unroll
  for (int off = 32; off; off >>= 1) m += __shfl_xor(m, off);
  m *= (1.0f / 64.0f);
  float d = x - m;
  float var = d * d;
#pragma unroll
  for (int off = 32; off; off >>= 1) var += __shfl_xor(var, off);
  var *= (1.0f / 64.0f);
  out[v * 64 + c] = d * rsqrtf(var + 1e-5f) * rg[c] + rb[c];
}

extern "C" void kernel_launch(void* const* d_in, const int* in_sizes, int n_in,
                              void* d_out, int out_size, void* d_ws, size_t ws_size,
                              hipStream_t stream) {
  const float* Z   = (const float*)d_in[0];
  const float* vm  = (const float*)d_in[1];
  const float* vf  = (const float*)d_in[2];
  const float* ea  = (const float*)d_in[3];
  const int*   ei  = (const int*)d_in[4];
  const int*   cur = (const int*)d_in[5];
  const float* nW  = (const float*)d_in[6];
  const float* nb  = (const float*)d_in[7];
  const float* pW1 = (const float*)d_in[8];
  const float* pb1 = (const float*)d_in[9];
  const float* pW2 = (const float*)d_in[10];
  const float* pb2 = (const float*)d_in[11];
  const float* rg  = (const float*)d_in[12];
  const float* rb  = (const float*)d_in[13];
  const float* W1[2] = {(const float*)d_in[14], (const float*)d_in[20]};
  const float* B1[2] = {(const float*)d_in[15], (const float*)d_in[21]};
  const float* W2[2] = {(const float*)d_in[16], (const float*)d_in[22]};
  const float* B2[2] = {(const float*)d_in[17], (const float*)d_in[23]};
  const float* G[2]  = {(const float*)d_in[18], (const float*)d_in[24]};
  const float* BE[2] = {(const float*)d_in[19], (const float*)d_in[25]};

  const int V_ = in_sizes[0] / 64;
  const int E_ = in_sizes[4] / 2;
  float* out = (float*)d_out;

  // Workspace layout (fp32): hA[V*64] | hB[V*64] | cnt[V] | props[64*64]
  float* hA    = (float*)d_ws;
  float* hB    = hA + (size_t)V_ * 64;
  float* cnt   = hB + (size_t)V_ * 64;
  float* props = cnt + V_;

  hipMemsetAsync(cnt, 0, (size_t)V_ * sizeof(float), stream);
  cnt_kernel<<<(E_ + 255) / 256, 256, 0, stream>>>(ei, cnt, E_);
  embed_kernel<<<1024, 256, 0, stream>>>(Z, vm, nW, nb, hA, V_);
  props_kernel<<<1, 64, 0, stream>>>(vf, pW1, pb1, pW2, pb2, props);

  // Layer 0: h = hA, agg -> hB, result LN in hB
  hipMemsetAsync(hB, 0, (size_t)V_ * 64 * sizeof(float), stream);
  edge_kernel<<<2048, 256, 0, stream>>>(hA, ea, ei, W1[0], B1[0], W2[0], B2[0], hB, E_);
  finalize_kernel<<<1024, 256, 0, stream>>>(hA, hB, cnt, G[0], BE[0], V_);

  // Layer 1: h = hB, agg -> hA, result LN in hA
  hipMemsetAsync(hA, 0, (size_t)V_ * 64 * sizeof(float), stream);
  edge_kernel<<<2048, 256, 0, stream>>>(hB, ea, ei, W1[1], B1[1], W2[1], B2[1], hA, E_);
  finalize_kernel<<<1024, 256, 0, stream>>>(hB, hA, cnt, G[1], BE[1], V_);

  final_kernel<<<64, 64, 0, stream>>>(hA, cur, props, rg, rb, out);
}

// Round 2
// 851.574 us; speedup vs baseline: 2.9547x; 2.9547x over previous
//
#include <hip/hip_runtime.h>
#include <hip/hip_bf16.h>

// V=50000, E=1600000, D=64, EF=16, node_in=74, NV=64 (derived at launch).

typedef __attribute__((ext_vector_type(8))) short short8b;   // 8 bf16 (4 VGPR)
typedef __attribute__((ext_vector_type(4))) float f32x4;     // MFMA C/D
typedef __attribute__((ext_vector_type(4))) unsigned int u32x4;

__device__ __forceinline__ void lgkm_wait() {
  asm volatile("s_waitcnt lgkmcnt(0)" ::: "memory");
}

static __device__ __forceinline__ short f2bf(float f) {
  __hip_bfloat16 h = __float2bfloat16(f);
  union { __hip_bfloat16 h; short s; } u; u.h = h; return u.s;
}

// ---------------------------------------------------------------- cnt kernel
__global__ void cnt_kernel(const int* __restrict__ ei, float* __restrict__ cnt, int E_) {
  int i = blockIdx.x * blockDim.x + threadIdx.x;
  if (i < E_) atomicAdd(&cnt[ei[E_ + i]], 1.0f);
}

// ------------------------------------------------------------- embed kernel
// h[r,c] = concat(Z[r,:],vm[r,:]) @ nW + nb ; writes f32 + bf16 mirror
__global__ __launch_bounds__(256) void embed_kernel(
    const float* __restrict__ Z, const float* __restrict__ vm,
    const float* __restrict__ nW, const float* __restrict__ nb,
    float* __restrict__ h, short* __restrict__ hbf, int V_) {
  __shared__ alignas(16) float zbuf[4][80];
  const int lane = threadIdx.x & 63;
  const int wid  = threadIdx.x >> 6;
  float wc[74];
#pragma unroll
  for (int k = 0; k < 74; ++k) wc[k] = nW[k * 64 + lane];
  const float bc = nb[lane];
  const int nw = (gridDim.x * blockDim.x) >> 6;
  const int w0 = (blockIdx.x * blockDim.x + threadIdx.x) >> 6;
  float* zrow = zbuf[wid];
  for (int r = w0; r < V_; r += nw) {
    lgkm_wait();
    zrow[lane] = Z[(size_t)r * 64 + lane];
    if (lane < 10) zrow[64 + lane] = vm[(size_t)r * 10 + lane];
    lgkm_wait();
    float acc0 = bc, acc1 = 0.0f;
    const float4* z4 = reinterpret_cast<const float4*>(zrow);
#pragma unroll
    for (int k4 = 0; k4 < 16; ++k4) {
      float4 z = z4[k4];
      acc0 = fmaf(z.x, wc[4 * k4 + 0], acc0);
      acc1 = fmaf(z.y, wc[4 * k4 + 1], acc1);
      acc0 = fmaf(z.z, wc[4 * k4 + 2], acc0);
      acc1 = fmaf(z.w, wc[4 * k4 + 3], acc1);
    }
#pragma unroll
    for (int k = 64; k < 74; ++k) acc0 = fmaf(zrow[k], wc[k], acc0);
    float y = acc0 + acc1;
    h[(size_t)r * 64 + lane] = y;
    hbf[(size_t)r * 64 + lane] = f2bf(y);
  }
}

// --------------------------------------------------------- edge MFMA kernel
// 16 edges per wave-tile. GEMM1: [16x96]x[96x64] (K padded 80->96), relu,
// GEMM2: [16x64]x[64x64]. Weight B-frags in registers; A-frags via
// wave-private LDS tiles (no barriers). fp32 atomicAdd scatter to agg[dst].
#define ZS 104   // z-tile row stride (bf16): 96 + 8 pad (bank spread)
#define TS 72    // t-tile row stride (bf16): 64 + 8 pad

__global__ __launch_bounds__(256) void edge_mfma_kernel(
    const short* __restrict__ hbf, const float* __restrict__ ea,
    const int* __restrict__ ei,
    const float* __restrict__ W1, const float* __restrict__ b1,
    const float* __restrict__ W2, const float* __restrict__ b2,
    float* __restrict__ agg, int E_) {
  __shared__ short zt[4][16][ZS];
  __shared__ short tt[4][16][TS];
  const int lane = threadIdx.x & 63;
  const int wid  = threadIdx.x >> 6;
  const int r = lane & 15;      // row within 16-tile
  const int g = lane >> 4;      // k/chunk group 0..3

  // Loop-invariant weight B-fragments: B[k][col], lane holds k=8g+i, col=n*16+r
  short8b w1f[4][3], w2f[4][2];
#pragma unroll
  for (int n = 0; n < 4; ++n)
#pragma unroll
    for (int s = 0; s < 3; ++s)
#pragma unroll
      for (int i = 0; i < 8; ++i) {
        int k = s * 32 + 8 * g + i;
        w1f[n][s][i] = f2bf(k < 80 ? W1[k * 64 + n * 16 + r] : 0.0f);
      }
#pragma unroll
  for (int n = 0; n < 4; ++n)
#pragma unroll
    for (int s = 0; s < 2; ++s)
#pragma unroll
      for (int i = 0; i < 8; ++i) {
        int k = s * 32 + 8 * g + i;
        w2f[n][s][i] = f2bf(W2[k * 64 + n * 16 + r]);
      }
  float b1v[4], b2v[4];
#pragma unroll
  for (int n = 0; n < 4; ++n) { b1v[n] = b1[n * 16 + r]; b2v[n] = b2[n * 16 + r]; }

  short (*z)[ZS] = zt[wid];
  short (*t)[TS] = tt[wid];
  // zero K-pad cols 80..103 once (never overwritten)
  for (int idx = lane; idx < 16 * 24; idx += 64) z[idx / 24][80 + idx % 24] = 0;

  const int ntiles = (E_ + 15) >> 4;
  const int nw = (gridDim.x * blockDim.x) >> 6;
  const int w0 = (blockIdx.x * blockDim.x + threadIdx.x) >> 6;

  for (int tile = w0; tile < ntiles; tile += nw) {
    const int e0 = tile << 4;
    const int er = min(e0 + r, E_ - 1);
    const int src = ei[er];
    // gather h_bf16 row src, 32B chunk g
    const char* hrow = reinterpret_cast<const char*>(hbf) + ((size_t)src * 64 + g * 16) * 2;
    const u32x4 hv0 = *reinterpret_cast<const u32x4*>(hrow);
    const u32x4 hv1 = *reinterpret_cast<const u32x4*>(hrow + 16);
    // edge_attr row er, float chunk g -> 4 bf16
    const float4 eav = reinterpret_cast<const float4*>(ea)[(size_t)er * 4 + g];
    short4 ev;
    ev.x = f2bf(eav.x); ev.y = f2bf(eav.y); ev.z = f2bf(eav.z); ev.w = f2bf(eav.w);

    lgkm_wait();  // prior-iteration LDS reads complete before overwrite
    *reinterpret_cast<u32x4*>(&z[r][g * 16])     = hv0;
    *reinterpret_cast<u32x4*>(&z[r][g * 16 + 8]) = hv1;
    *reinterpret_cast<short4*>(&z[r][64 + g * 4]) = ev;
    lgkm_wait();  // writes visible within wave

    // A-frags: lane holds A[r][k=s*32+8g+i]
    short8b a0 = *reinterpret_cast<short8b*>(&z[r][0 * 32 + 8 * g]);
    short8b a1 = *reinterpret_cast<short8b*>(&z[r][1 * 32 + 8 * g]);
    short8b a2 = *reinterpret_cast<short8b*>(&z[r][2 * 32 + 8 * g]);

    f32x4 acc[4];
#pragma unroll
    for (int n = 0; n < 4; ++n) {
      acc[n] = f32x4{b1v[n], b1v[n], b1v[n], b1v[n]};
      acc[n] = __builtin_amdgcn_mfma_f32_16x16x32_bf16(a0, w1f[n][0], acc[n], 0, 0, 0);
      acc[n] = __builtin_amdgcn_mfma_f32_16x16x32_bf16(a1, w1f[n][1], acc[n], 0, 0, 0);
      acc[n] = __builtin_amdgcn_mfma_f32_16x16x32_bf16(a2, w1f[n][2], acc[n], 0, 0, 0);
    }
    lgkm_wait();  // a-frag reads done before t-tile writes (t aliases nothing, but keep order cheap)
    // relu + bf16, write T: D layout row=4g+i, col=n*16+r
#pragma unroll
    for (int n = 0; n < 4; ++n)
#pragma unroll
      for (int i = 0; i < 4; ++i)
        t[4 * g + i][n * 16 + r] = f2bf(fmaxf(acc[n][i], 0.0f));
    lgkm_wait();

    short8b t0 = *reinterpret_cast<short8b*>(&t[r][0 * 32 + 8 * g]);
    short8b t1 = *reinterpret_cast<short8b*>(&t[r][1 * 32 + 8 * g]);

    f32x4 o[4];
#pragma unroll
    for (int n = 0; n < 4; ++n) {
      o[n] = f32x4{b2v[n], b2v[n], b2v[n], b2v[n]};
      o[n] = __builtin_amdgcn_mfma_f32_16x16x32_bf16(t0, w2f[n][0], o[n], 0, 0, 0);
      o[n] = __builtin_amdgcn_mfma_f32_16x16x32_bf16(t1, w2f[n][1], o[n], 0, 0, 0);
    }
    // scatter: output row 4g+i is edge e0+4g+i
    int dstq[4];
#pragma unroll
    for (int i = 0; i < 4; ++i) {
      int e = e0 + 4 * g + i;
      dstq[i] = (e < E_) ? ei[E_ + e] : -1;
    }
#pragma unroll
    for (int i = 0; i < 4; ++i) {
      if (dstq[i] >= 0) {
        float* base = agg + (size_t)dstq[i] * 64 + r;
#pragma unroll
        for (int n = 0; n < 4; ++n) atomicAdd(base + n * 16, o[n][i]);
      }
    }
  }
}

// ---------------------------------------------------------- finalize kernel
// agg[r,:] = LN(h[r,:] + agg[r,:]/max(cnt[r],1))*g + be ; optional bf16 out
__global__ __launch_bounds__(256) void finalize_kernel(
    const float* __restrict__ h, float* __restrict__ agg,
    const float* __restrict__ cnt, const float* __restrict__ g,
    const float* __restrict__ be, short* __restrict__ hbf, int V_) {
  const int lane = threadIdx.x & 63;
  const int nw = (gridDim.x * blockDim.x) >> 6;
  const int w0 = (blockIdx.x * blockDim.x + threadIdx.x) >> 6;
  const float gc = g[lane], bc = be[lane];
  for (int r = w0; r < V_; r += nw) {
    float x = h[(size_t)r * 64 + lane] +
              agg[(size_t)r * 64 + lane] / fmaxf(cnt[r], 1.0f);
    float m = x;
#pragma unroll
    for (int off = 32; off; off >>= 1) m += __shfl_xor(m, off);
    m *= (1.0f / 64.0f);
    float d = x - m;
    float v = d * d;
#pragma unroll
    for (int off = 32; off; off >>= 1) v += __shfl_xor(v, off);
    v *= (1.0f / 64.0f);
    float y = d * rsqrtf(v + 1e-5f) * gc + bc;
    agg[(size_t)r * 64 + lane] = y;
    if (hbf) hbf[(size_t)r * 64 + lane] = f2bf(y);
  }
}

// ------------------------------------------------------------- props kernel
__global__ void props_kernel(const float* __restrict__ vf,
                             const float* __restrict__ pW1, const float* __restrict__ pb1,
                             const float* __restrict__ pW2, const float* __restrict__ pb2,
                             float* __restrict__ props) {
  __shared__ float tbuf[64];
  const int c = threadIdx.x;  // 0..63
  float w1c[8], w2c[64];
#pragma unroll
  for (int i = 0; i < 8; ++i) w1c[i] = pW1[i * 64 + c];
#pragma unroll
  for (int k = 0; k < 64; ++k) w2c[k] = pW2[k * 64 + c];
  const float b1c = pb1[c], b2c = pb2[c];
  for (int v = 0; v < 64; ++v) {
    float acc = b1c;
#pragma unroll
    for (int i = 0; i < 8; ++i) acc = fmaf(vf[v * 8 + i], w1c[i], acc);
    tbuf[c] = fmaxf(acc, 0.0f);
    __syncthreads();
    float s = b2c;
#pragma unroll
    for (int k = 0; k < 64; ++k) s = fmaf(tbuf[k], w2c[k], s);
    props[v * 64 + c] = s;
    __syncthreads();
  }
}

// -------------------------------------------------------------- final kernel
__global__ void final_kernel(const float* __restrict__ h, const int* __restrict__ cur,
                             const float* __restrict__ props,
                             const float* __restrict__ rg, const float* __restrict__ rb,
                             float* __restrict__ out) {
  const int v = blockIdx.x;
  const int c = threadIdx.x;  // 64 threads
  const int node = cur[v];
  float x = h[(size_t)node * 64 + c] + props[v * 64 + c];
  float m = x;
#pragma unroll
  for (int off = 32; off; off >>= 1) m += __shfl_xor(m, off);
  m *= (1.0f / 64.0f);
  float d = x - m;
  float var = d * d;
#pragma unroll
  for (int off = 32; off; off >>= 1) var += __shfl_xor(var, off);
  var *= (1.0f / 64.0f);
  out[v * 64 + c] = d * rsqrtf(var + 1e-5f) * rg[c] + rb[c];
}

extern "C" void kernel_launch(void* const* d_in, const int* in_sizes, int n_in,
                              void* d_out, int out_size, void* d_ws, size_t ws_size,
                              hipStream_t stream) {
  const float* Z   = (const float*)d_in[0];
  const float* vm  = (const float*)d_in[1];
  const float* vf  = (const float*)d_in[2];
  const float* ea  = (const float*)d_in[3];
  const int*   ei  = (const int*)d_in[4];
  const int*   cur = (const int*)d_in[5];
  const float* nW  = (const float*)d_in[6];
  const float* nb  = (const float*)d_in[7];
  const float* pW1 = (const float*)d_in[8];
  const float* pb1 = (const float*)d_in[9];
  const float* pW2 = (const float*)d_in[10];
  const float* pb2 = (const float*)d_in[11];
  const float* rg  = (const float*)d_in[12];
  const float* rb  = (const float*)d_in[13];
  const float* W1[2] = {(const float*)d_in[14], (const float*)d_in[20]};
  const float* B1[2] = {(const float*)d_in[15], (const float*)d_in[21]};
  const float* W2[2] = {(const float*)d_in[16], (const float*)d_in[22]};
  const float* B2[2] = {(const float*)d_in[17], (const float*)d_in[23]};
  const float* G[2]  = {(const float*)d_in[18], (const float*)d_in[24]};
  const float* BE[2] = {(const float*)d_in[19], (const float*)d_in[25]};

  const int V_ = in_sizes[0] / 64;
  const int E_ = in_sizes[4] / 2;
  float* out = (float*)d_out;

  // ws layout (floats): hA[V*64] | hB[V*64] | hAbf(V*32) | hBbf(V*32) | cnt[V] | props[4096]
  float* hA    = (float*)d_ws;
  float* hB    = hA + (size_t)V_ * 64;
  short* hAbf  = (short*)(hB + (size_t)V_ * 64);
  short* hBbf  = hAbf + (size_t)V_ * 64;
  float* cnt   = (float*)(hBbf + (size_t)V_ * 64);
  float* props = cnt + V_;

  hipMemsetAsync(cnt, 0, (size_t)V_ * sizeof(float), stream);
  cnt_kernel<<<(E_ + 255) / 256, 256, 0, stream>>>(ei, cnt, E_);
  embed_kernel<<<1024, 256, 0, stream>>>(Z, vm, nW, nb, hA, hAbf, V_);
  props_kernel<<<1, 64, 0, stream>>>(vf, pW1, pb1, pW2, pb2, props);

  // Layer 0: gather hAbf, agg -> hB, LN -> hB (f32) + hBbf (bf16)
  hipMemsetAsync(hB, 0, (size_t)V_ * 64 * sizeof(float), stream);
  edge_mfma_kernel<<<1024, 256, 0, stream>>>(hAbf, ea, ei, W1[0], B1[0], W2[0], B2[0], hB, E_);
  finalize_kernel<<<1024, 256, 0, stream>>>(hA, hB, cnt, G[0], BE[0], hBbf, V_);

  // Layer 1: gather hBbf, agg -> hA, LN -> hA (f32)
  hipMemsetAsync(hA, 0, (size_t)V_ * 64 * sizeof(float), stream);
  edge_mfma_kernel<<<1024, 256, 0, stream>>>(hBbf, ea, ei, W1[1], B1[1], W2[1], B2[1], hA, E_);
  finalize_kernel<<<1024, 256, 0, stream>>>(hB, hA, cnt, G[1], BE[1], (short*)nullptr, V_);

  final_kernel<<<64, 64, 0, stream>>>(hA, cur, props, rg, rb, out);
}

// Round 3
// 492.371 us; speedup vs baseline: 5.1103x; 1.7295x over previous
//
#include <hip/hip_runtime.h>
#include <hip/hip_bf16.h>

// V=50000, E=1600000, D=64, EF=16, node_in=74, NV=64 (derived at launch).
// Strategy: dst-CSR counting sort (once), then per-layer:
//   edge kernel: S[v] = sum_{e->v} relu([h[src],ea] @ W1 + b1)   (MFMA, no atomics)
//   node kernel: h' = LN(h + (S@W2)/deg + b2 [deg>0])            (MFMA + fused LN)
// using linearity of W2: segsum(relu@W2 + b2) = segsum(relu)@W2 + deg*b2.

typedef __attribute__((ext_vector_type(8))) short short8b;   // 8 bf16
typedef __attribute__((ext_vector_type(4))) float f32x4;     // MFMA C/D
typedef __attribute__((ext_vector_type(4))) unsigned int u32x4;

static __device__ __forceinline__ short f2bf(float f) {
  __hip_bfloat16 h = __float2bfloat16(f);
  union { __hip_bfloat16 h; short s; } u; u.h = h; return u.s;
}

// ------------------------------------------------------------ CSR build
__global__ void deg_kernel(const int* __restrict__ ei, int* __restrict__ deg, int E_) {
  int i = blockIdx.x * blockDim.x + threadIdx.x;
  if (i < E_) atomicAdd(&deg[ei[E_ + i]], 1);
}

// offsets via in-wave scan + one atomic per wave (bucket ORDER is arbitrary,
// which is fine: buckets only need to be disjoint & contiguous).
__global__ void off_kernel(const int* __restrict__ deg, int* __restrict__ off,
                           int* __restrict__ cursor, int* __restrict__ gtotal, int V_) {
  int v = blockIdx.x * blockDim.x + threadIdx.x;
  int lane = threadIdx.x & 63;
  int d = (v < V_) ? deg[v] : 0;
  int x = d;
#pragma unroll
  for (int o = 1; o < 64; o <<= 1) {
    int y = __shfl_up(x, o);
    if (lane >= o) x += y;
  }
  int total = __shfl(x, 63);
  int excl = x - d;
  int base = 0;
  if (lane == 0) base = atomicAdd(gtotal, total);
  base = __shfl(base, 0);
  if (v < V_) { off[v] = base + excl; cursor[v] = base + excl; }
}

__global__ void scatter_kernel(const int* __restrict__ ei, const float* __restrict__ ea,
                               int* __restrict__ cursor, int* __restrict__ srcs,
                               short* __restrict__ eas, int E_) {
  int i = blockIdx.x * blockDim.x + threadIdx.x;
  if (i >= E_) return;
  int dst = ei[E_ + i];
  int pos = atomicAdd(&cursor[dst], 1);
  srcs[pos] = ei[i];
  const float4* row = reinterpret_cast<const float4*>(ea + (size_t)i * 16);
  float4 q0 = row[0], q1 = row[1], q2 = row[2], q3 = row[3];
  short8b s0, s1;
  s0[0]=f2bf(q0.x); s0[1]=f2bf(q0.y); s0[2]=f2bf(q0.z); s0[3]=f2bf(q0.w);
  s0[4]=f2bf(q1.x); s0[5]=f2bf(q1.y); s0[6]=f2bf(q1.z); s0[7]=f2bf(q1.w);
  s1[0]=f2bf(q2.x); s1[1]=f2bf(q2.y); s1[2]=f2bf(q2.z); s1[3]=f2bf(q2.w);
  s1[4]=f2bf(q3.x); s1[5]=f2bf(q3.y); s1[6]=f2bf(q3.z); s1[7]=f2bf(q3.w);
  short8b* out = reinterpret_cast<short8b*>(eas + (size_t)pos * 16);
  out[0] = s0; out[1] = s1;
}

// ------------------------------------------------------- embed (MFMA tiles)
// h[v,:] = concat(Z[v,:],vm[v,:]) @ nW + nb ; K=74 padded to 96.
__global__ __launch_bounds__(256) void embed_mfma(
    const float* __restrict__ Z, const float* __restrict__ vm,
    const float* __restrict__ nW, const float* __restrict__ nb,
    float* __restrict__ h, short* __restrict__ hbf, int V_) {
  const int lane = threadIdx.x & 63;
  const int r = lane & 15, g = lane >> 4;
  short8b wf[4][3];
#pragma unroll
  for (int n = 0; n < 4; ++n)
#pragma unroll
    for (int s = 0; s < 3; ++s)
#pragma unroll
      for (int i = 0; i < 8; ++i) {
        int k = s * 32 + 8 * g + i;
        wf[n][s][i] = f2bf(k < 74 ? nW[k * 64 + n * 16 + r] : 0.0f);
      }
  float nb4[4];
#pragma unroll
  for (int n = 0; n < 4; ++n) nb4[n] = nb[n * 16 + r];

  const int ntiles = (V_ + 15) >> 4;
  const int nw = (gridDim.x * blockDim.x) >> 6;
  const int w0 = (blockIdx.x * blockDim.x + threadIdx.x) >> 6;
  for (int tile = w0; tile < ntiles; tile += nw) {
    const int v0 = tile << 4;
    const int vr = min(v0 + r, V_ - 1);
    const float* zrow = Z + (size_t)vr * 64;
    const float4* z4 = reinterpret_cast<const float4*>(zrow);
    float4 p0 = z4[2 * g], p1 = z4[2 * g + 1];
    float4 p2 = z4[8 + 2 * g], p3 = z4[9 + 2 * g];
    short8b a0, a1, a2;
    a0[0]=f2bf(p0.x); a0[1]=f2bf(p0.y); a0[2]=f2bf(p0.z); a0[3]=f2bf(p0.w);
    a0[4]=f2bf(p1.x); a0[5]=f2bf(p1.y); a0[6]=f2bf(p1.z); a0[7]=f2bf(p1.w);
    a1[0]=f2bf(p2.x); a1[1]=f2bf(p2.y); a1[2]=f2bf(p2.z); a1[3]=f2bf(p2.w);
    a1[4]=f2bf(p3.x); a1[5]=f2bf(p3.y); a1[6]=f2bf(p3.z); a1[7]=f2bf(p3.w);
    const float* vrow = vm + (size_t)vr * 10;
#pragma unroll
    for (int i = 0; i < 8; ++i) a2[i] = 0;
    if (g == 0) {
#pragma unroll
      for (int i = 0; i < 8; ++i) a2[i] = f2bf(vrow[i]);
    } else if (g == 1) {
      a2[0] = f2bf(vrow[8]); a2[1] = f2bf(vrow[9]);
    }
    f32x4 acc[4];
#pragma unroll
    for (int n = 0; n < 4; ++n) {
      acc[n] = f32x4{nb4[n], nb4[n], nb4[n], nb4[n]};
      acc[n] = __builtin_amdgcn_mfma_f32_16x16x32_bf16(a0, wf[n][0], acc[n], 0, 0, 0);
      acc[n] = __builtin_amdgcn_mfma_f32_16x16x32_bf16(a1, wf[n][1], acc[n], 0, 0, 0);
      acc[n] = __builtin_amdgcn_mfma_f32_16x16x32_bf16(a2, wf[n][2], acc[n], 0, 0, 0);
    }
#pragma unroll
    for (int i = 0; i < 4; ++i) {
      int u = v0 + 4 * g + i;
      if (u < V_) {
#pragma unroll
        for (int n = 0; n < 4; ++n) {
          h[(size_t)u * 64 + n * 16 + r] = acc[n][i];
          hbf[(size_t)u * 64 + n * 16 + r] = f2bf(acc[n][i]);
        }
      }
    }
  }
}

// ---------------------------------------------------------- edge S kernel
// One wave per node: S[v] = sum over CSR bucket of relu([h[src],ea]@W1+b1).
// GEMM1 tiles of 16 edges, K=80 padded to 96. No LDS, no atomics.
__global__ __launch_bounds__(256) void edge_s_kernel(
    const short* __restrict__ hbf, const int* __restrict__ srcs,
    const short* __restrict__ eas, const int* __restrict__ off,
    const int* __restrict__ deg,
    const float* __restrict__ W1, const float* __restrict__ b1,
    short* __restrict__ S_bf, int V_) {
  const int lane = threadIdx.x & 63;
  const int r = lane & 15, g = lane >> 4;
  short8b w1f[4][3];
#pragma unroll
  for (int n = 0; n < 4; ++n)
#pragma unroll
    for (int s = 0; s < 3; ++s)
#pragma unroll
      for (int i = 0; i < 8; ++i) {
        int k = s * 32 + 8 * g + i;
        w1f[n][s][i] = f2bf(k < 80 ? W1[k * 64 + n * 16 + r] : 0.0f);
      }
  float b1v[4];
#pragma unroll
  for (int n = 0; n < 4; ++n) b1v[n] = b1[n * 16 + r];

  const int nw = (gridDim.x * blockDim.x) >> 6;
  const int w0 = (blockIdx.x * blockDim.x + threadIdx.x) >> 6;
  for (int v = w0; v < V_; v += nw) {
    const int o = off[v], d = deg[v];
    f32x4 Sacc[4];
#pragma unroll
    for (int n = 0; n < 4; ++n) Sacc[n] = f32x4{0.f, 0.f, 0.f, 0.f};
    const int nt = (d + 15) >> 4;
    for (int t = 0; t < nt; ++t) {
      const int row = t * 16 + r;
      const int p = o + (row < d ? row : d - 1);
      const int src = srcs[p];
      const short* hrow = hbf + (size_t)src * 64;
      short8b a0 = *reinterpret_cast<const short8b*>(hrow + 8 * g);
      short8b a1 = *reinterpret_cast<const short8b*>(hrow + 32 + 8 * g);
      short8b a2;
#pragma unroll
      for (int i = 0; i < 8; ++i) a2[i] = 0;
      if (g < 2) a2 = *reinterpret_cast<const short8b*>(eas + (size_t)p * 16 + 8 * g);
      f32x4 acc[4];
#pragma unroll
      for (int n = 0; n < 4; ++n) {
        acc[n] = f32x4{b1v[n], b1v[n], b1v[n], b1v[n]};
        acc[n] = __builtin_amdgcn_mfma_f32_16x16x32_bf16(a0, w1f[n][0], acc[n], 0, 0, 0);
        acc[n] = __builtin_amdgcn_mfma_f32_16x16x32_bf16(a1, w1f[n][1], acc[n], 0, 0, 0);
        acc[n] = __builtin_amdgcn_mfma_f32_16x16x32_bf16(a2, w1f[n][2], acc[n], 0, 0, 0);
      }
      const int rowbase = t * 16 + 4 * g;
#pragma unroll
      for (int i = 0; i < 4; ++i) {
        if (rowbase + i < d) {
#pragma unroll
          for (int n = 0; n < 4; ++n) Sacc[n][i] += fmaxf(acc[n][i], 0.0f);
        }
      }
    }
    float s4[4];
#pragma unroll
    for (int n = 0; n < 4; ++n) {
      s4[n] = (Sacc[n][0] + Sacc[n][1]) + (Sacc[n][2] + Sacc[n][3]);
      s4[n] += __shfl_xor(s4[n], 16);
      s4[n] += __shfl_xor(s4[n], 32);
    }
    float val = (g == 0) ? s4[0] : (g == 1) ? s4[1] : (g == 2) ? s4[2] : s4[3];
    S_bf[(size_t)v * 64 + 16 * g + r] = f2bf(val);
  }
}

// -------------------------------------------------- node GEMM + LN kernel
// h'[u] = LN(h[u] + [deg>0]((S[u]@W2)/deg + b2)) * gam + bet
__global__ __launch_bounds__(256) void ln_node_kernel(
    const short* __restrict__ S_bf, const float* __restrict__ h_in,
    const int* __restrict__ deg,
    const float* __restrict__ W2, const float* __restrict__ b2,
    const float* __restrict__ gam, const float* __restrict__ bet,
    float* __restrict__ h_out, short* __restrict__ hbf_out, int V_) {
  const int lane = threadIdx.x & 63;
  const int r = lane & 15, g = lane >> 4;
  short8b w2f[4][2];
#pragma unroll
  for (int n = 0; n < 4; ++n)
#pragma unroll
    for (int s = 0; s < 2; ++s)
#pragma unroll
      for (int i = 0; i < 8; ++i) {
        int k = s * 32 + 8 * g + i;
        w2f[n][s][i] = f2bf(W2[k * 64 + n * 16 + r]);
      }
  float b2v[4], gv[4], bv[4];
#pragma unroll
  for (int n = 0; n < 4; ++n) {
    b2v[n] = b2[n * 16 + r]; gv[n] = gam[n * 16 + r]; bv[n] = bet[n * 16 + r];
  }
  const int ntiles = (V_ + 15) >> 4;
  const int nw = (gridDim.x * blockDim.x) >> 6;
  const int w0 = (blockIdx.x * blockDim.x + threadIdx.x) >> 6;
  for (int tile = w0; tile < ntiles; tile += nw) {
    const int v0 = tile << 4;
    const int vr = min(v0 + r, V_ - 1);
    const short* srow = S_bf + (size_t)vr * 64;
    short8b a0 = *reinterpret_cast<const short8b*>(srow + 8 * g);
    short8b a1 = *reinterpret_cast<const short8b*>(srow + 32 + 8 * g);
    f32x4 acc[4];
#pragma unroll
    for (int n = 0; n < 4; ++n) {
      acc[n] = f32x4{0.f, 0.f, 0.f, 0.f};
      acc[n] = __builtin_amdgcn_mfma_f32_16x16x32_bf16(a0, w2f[n][0], acc[n], 0, 0, 0);
      acc[n] = __builtin_amdgcn_mfma_f32_16x16x32_bf16(a1, w2f[n][1], acc[n], 0, 0, 0);
    }
    float x[4][4];  // [i][n]
    float pm[4], pq[4];
#pragma unroll
    for (int i = 0; i < 4; ++i) {
      int u = min(v0 + 4 * g + i, V_ - 1);
      int di = deg[u];
      float inv = di > 0 ? 1.0f / (float)di : 0.0f;
      float hasb = di > 0 ? 1.0f : 0.0f;
      float s = 0.f, q = 0.f;
#pragma unroll
      for (int n = 0; n < 4; ++n) {
        float hv = h_in[(size_t)u * 64 + n * 16 + r];
        float xx = hv + acc[n][i] * inv + hasb * b2v[n];
        x[i][n] = xx;
        s += xx; q += xx * xx;
      }
      pm[i] = s; pq[i] = q;
    }
#pragma unroll
    for (int o = 1; o < 16; o <<= 1) {
#pragma unroll
      for (int i = 0; i < 4; ++i) {
        pm[i] += __shfl_xor(pm[i], o);
        pq[i] += __shfl_xor(pq[i], o);
      }
    }
#pragma unroll
    for (int i = 0; i < 4; ++i) {
      int u = v0 + 4 * g + i;
      if (u < V_) {
        float mean = pm[i] * (1.0f / 64.0f);
        float var = pq[i] * (1.0f / 64.0f) - mean * mean;
        float rs = rsqrtf(var + 1e-5f);
#pragma unroll
        for (int n = 0; n < 4; ++n) {
          float y = (x[i][n] - mean) * rs * gv[n] + bv[n];
          h_out[(size_t)u * 64 + n * 16 + r] = y;
          if (hbf_out) hbf_out[(size_t)u * 64 + n * 16 + r] = f2bf(y);
        }
      }
    }
  }
}

// ------------------------------------------------------------- props kernel
__global__ void props_kernel(const float* __restrict__ vf,
                             const float* __restrict__ pW1, const float* __restrict__ pb1,
                             const float* __restrict__ pW2, const float* __restrict__ pb2,
                             float* __restrict__ props) {
  __shared__ float tbuf[64];
  const int c = threadIdx.x;  // 0..63
  float w1c[8], w2c[64];
#pragma unroll
  for (int i = 0; i < 8; ++i) w1c[i] = pW1[i * 64 + c];
#pragma unroll
  for (int k = 0; k < 64; ++k) w2c[k] = pW2[k * 64 + c];
  const float b1c = pb1[c], b2c = pb2[c];
  for (int v = 0; v < 64; ++v) {
    float acc = b1c;
#pragma unroll
    for (int i = 0; i < 8; ++i) acc = fmaf(vf[v * 8 + i], w1c[i], acc);
    tbuf[c] = fmaxf(acc, 0.0f);
    __syncthreads();
    float s = b2c;
#pragma unroll
    for (int k = 0; k < 64; ++k) s = fmaf(tbuf[k], w2c[k], s);
    props[v * 64 + c] = s;
    __syncthreads();
  }
}

// -------------------------------------------------------------- final kernel
__global__ void final_kernel(const float* __restrict__ h, const int* __restrict__ cur,
                             const float* __restrict__ props,
                             const float* __restrict__ rg, const float* __restrict__ rb,
                             float* __restrict__ out) {
  const int v = blockIdx.x;
  const int c = threadIdx.x;  // 64 threads
  const int node = cur[v];
  float x = h[(size_t)node * 64 + c] + props[v * 64 + c];
  float m = x;
#pragma unroll
  for (int off = 32; off; off >>= 1) m += __shfl_xor(m, off);
  m *= (1.0f / 64.0f);
  float d = x - m;
  float var = d * d;
#pragma unroll
  for (int off = 32; off; off >>= 1) var += __shfl_xor(var, off);
  var *= (1.0f / 64.0f);
  out[v * 64 + c] = d * rsqrtf(var + 1e-5f) * rg[c] + rb[c];
}

extern "C" void kernel_launch(void* const* d_in, const int* in_sizes, int n_in,
                              void* d_out, int out_size, void* d_ws, size_t ws_size,
                              hipStream_t stream) {
  const float* Z   = (const float*)d_in[0];
  const float* vm  = (const float*)d_in[1];
  const float* vf  = (const float*)d_in[2];
  const float* ea  = (const float*)d_in[3];
  const int*   ei  = (const int*)d_in[4];
  const int*   cur = (const int*)d_in[5];
  const float* nW  = (const float*)d_in[6];
  const float* nb  = (const float*)d_in[7];
  const float* pW1 = (const float*)d_in[8];
  const float* pb1 = (const float*)d_in[9];
  const float* pW2 = (const float*)d_in[10];
  const float* pb2 = (const float*)d_in[11];
  const float* rg  = (const float*)d_in[12];
  const float* rb  = (const float*)d_in[13];
  const float* W1[2] = {(const float*)d_in[14], (const float*)d_in[20]};
  const float* B1[2] = {(const float*)d_in[15], (const float*)d_in[21]};
  const float* W2[2] = {(const float*)d_in[16], (const float*)d_in[22]};
  const float* B2[2] = {(const float*)d_in[17], (const float*)d_in[23]};
  const float* G[2]  = {(const float*)d_in[18], (const float*)d_in[24]};
  const float* BE[2] = {(const float*)d_in[19], (const float*)d_in[25]};

  const int V_ = in_sizes[0] / 64;
  const int E_ = in_sizes[4] / 2;
  float* out = (float*)d_out;

  // ---- workspace layout (bytes, 256-aligned chunks)
  char* p = (char*)d_ws;
  auto take = [&](size_t bytes) { char* q = p; p += (bytes + 255) & ~(size_t)255; return q; };
  float* hA    = (float*)take((size_t)V_ * 64 * 4);
  float* hB    = (float*)take((size_t)V_ * 64 * 4);
  short* hAbf  = (short*)take((size_t)V_ * 64 * 2);
  short* hBbf  = (short*)take((size_t)V_ * 64 * 2);
  short* Sbf   = (short*)take((size_t)V_ * 64 * 2);
  int*   srcs  = (int*)take((size_t)E_ * 4);
  short* eas   = (short*)take((size_t)E_ * 16 * 2);
  int*   deg   = (int*)take((size_t)V_ * 4);
  int*   off   = (int*)take((size_t)V_ * 4);
  int*   cursor= (int*)take((size_t)V_ * 4);
  int*   gtotal= (int*)take(256);
  float* props = (float*)take(64 * 64 * 4);

  // ---- CSR build (once; shared by both layers)
  hipMemsetAsync(deg, 0, (size_t)V_ * 4, stream);
  hipMemsetAsync(gtotal, 0, 4, stream);
  deg_kernel<<<(E_ + 255) / 256, 256, 0, stream>>>(ei, deg, E_);
  off_kernel<<<(V_ + 255) / 256, 256, 0, stream>>>(deg, off, cursor, gtotal, V_);
  scatter_kernel<<<(E_ + 255) / 256, 256, 0, stream>>>(ei, ea, cursor, srcs, eas, E_);

  // ---- embed + props
  embed_mfma<<<784, 256, 0, stream>>>(Z, vm, nW, nb, hA, hAbf, V_);
  props_kernel<<<1, 64, 0, stream>>>(vf, pW1, pb1, pW2, pb2, props);

  // ---- layer 0
  edge_s_kernel<<<1024, 256, 0, stream>>>(hAbf, srcs, eas, off, deg, W1[0], B1[0], Sbf, V_);
  ln_node_kernel<<<784, 256, 0, stream>>>(Sbf, hA, deg, W2[0], B2[0], G[0], BE[0], hB, hBbf, V_);

  // ---- layer 1
  edge_s_kernel<<<1024, 256, 0, stream>>>(hBbf, srcs, eas, off, deg, W1[1], B1[1], Sbf, V_);
  ln_node_kernel<<<784, 256, 0, stream>>>(Sbf, hB, deg, W2[1], B2[1], G[1], BE[1], hA, (short*)nullptr, V_);

  final_kernel<<<64, 64, 0, stream>>>(hA, cur, props, rg, rb, out);
}